// Round 2
// baseline (33.798 us; speedup 1.0000x reference)
//
#include <hip/hip_runtime.h>
#include <math.h>

#define NB   16
#define NA   5
#define NC   20
#define NG   32
#define HWSZ 4096
#define WDIM 64
#define NCH  25          // 5 + NC
#define OBJ_SCALE 5.0f
#define IOU_THR   0.6f

// Single self-contained kernel: one thread per (b,a,cell). No d_ws usage.
// First 32 lanes of each block redundantly compute the per-gt prep for this
// block's batch into LDS (13 fields x 32 gts), then all 256 threads do the
// per-cell loss, block-reduce, one atomicAdd.
__global__ __launch_bounds__(256) void yolo_loss(
    const float* __restrict__ output,
    const float* __restrict__ target,
    const void*  __restrict__ gt_valid_raw,
    const float* __restrict__ anchors,
    float* __restrict__ out)
{
    // s fields: 0..3 gt x1,y1,x2,y2 | 4 area | 5 valid | 6 best_n | 7 cell
    //           8..11 tx,ty,tw,th   | 12 tcls
    __shared__ float s[13][NG];
    __shared__ float wsum[4];
    __shared__ int f1, f23;

    int tid  = threadIdx.x;
    int idx  = blockIdx.x * 256 + tid;
    int b    = idx / (NA * HWSZ);      // uniform per block (20480 % 256 == 0)
    int rem  = idx % (NA * HWSZ);
    int a    = rem / HWSZ;             // uniform per block
    int cell = rem % HWSZ;

    if (tid == 0) { f1 = 0; f23 = 0; }
    __syncthreads();

    // --- sniff gt_valid dtype. Reads bytes [0,512): in-bounds for u8 (512B),
    // i32 (2048B), f32 (2048B). u8 bool -> nonzero bytes at all (i&3) -> f1.
    // f32 1.0f -> bytes 00 00 80 3F -> nonzero only at (i&3)>=2 -> f23.
    // i32 1    -> bytes 01 00 00 00 -> nonzero only at (i&3)==0 -> neither.
    const unsigned char* bytes = (const unsigned char*)gt_valid_raw;
    {
        unsigned char c0 = bytes[tid] | bytes[tid + 256];
        int m4 = tid & 3;
        if (c0) { if (m4 == 1) f1 = 1; else if (m4 >= 2) f23 = 1; }
    }
    __syncthreads();

    if (tid < NG) {
        int t = b * NG + tid;
        float valid;
        if (f1)       valid = bytes[t] ? 1.0f : 0.0f;
        else if (f23) valid = (((const float*)gt_valid_raw)[t] != 0.0f) ? 1.0f : 0.0f;
        else          valid = (((const int*)gt_valid_raw)[t]   != 0)    ? 1.0f : 0.0f;

        const float* tg = target + t * 5;
        float x = tg[0], y = tg[1], w = tg[2], h = tg[3], cls = tg[4];
        const float inv = 1.0f / 32.0f;
        float gx = (x + 0.5f * w) * inv;
        float gy = (y + 0.5f * h) * inv;
        float gw = w * inv, gh = h * inv;
        float garea = gw * gh;

        // best anchor: IOU of (0,0,gw,gh) vs (0,0,aw,ah); first-max wins
        int best = 0; float bi = -1.0f, baw = 1.0f, bah = 1.0f;
        #pragma unroll
        for (int n = 0; n < NA; ++n) {
            float aw_ = anchors[2*n], ah_ = anchors[2*n + 1];
            float inter = fminf(gw, aw_) * fminf(gh, ah_);
            float iou   = inter / (garea + aw_ * ah_ - inter);
            if (iou > bi) { bi = iou; best = n; baw = aw_; bah = ah_; }
        }
        int gi = min(max((int)gx, 0), WDIM - 1);
        int gj = min(max((int)gy, 0), WDIM - 1);

        s[ 0][tid] = gx - 0.5f * gw;
        s[ 1][tid] = gy - 0.5f * gh;
        s[ 2][tid] = gx + 0.5f * gw;
        s[ 3][tid] = gy + 0.5f * gh;
        s[ 4][tid] = garea;
        s[ 5][tid] = valid;
        s[ 6][tid] = (float)best;
        s[ 7][tid] = (float)(gj * WDIM + gi);
        s[ 8][tid] = gx - (float)gi;
        s[ 9][tid] = gy - (float)gj;
        s[10][tid] = logf(fmaxf(gw, 1.0f) / baw);
        s[11][tid] = logf(fmaxf(gh, 1.0f) / bah);
        s[12][tid] = cls;
    }
    __syncthreads();

    const float* base = output + ((size_t)(b * NA + a) * NCH) * HWSZ + cell;
    float ox = base[0];
    float oy = base[1 * HWSZ];
    float ow = base[2 * HWSZ];
    float oh = base[3 * HWSZ];
    float oc = base[4 * HWSZ];

    float sx   = 1.0f / (1.0f + __expf(-ox));
    float sy   = 1.0f / (1.0f + __expf(-oy));
    float conf = 1.0f / (1.0f + __expf(-oc));
    float pw = __expf(ow) * anchors[2 * a];
    float ph = __expf(oh) * anchors[2 * a + 1];
    float px = sx + (float)(cell & (WDIM - 1));
    float py = sy + (float)(cell >> 6);
    float px1 = px - 0.5f * pw, px2 = px + 0.5f * pw;
    float py1 = py - 0.5f * ph, py2 = py + 0.5f * ph;
    float parea = pw * ph;

    bool  ignore = false;
    int   match  = -1;
    float iou_m  = 0.0f;
    #pragma unroll
    for (int g = 0; g < NG; ++g) {
        float dx = fminf(px2, s[2][g]) - fmaxf(px1, s[0][g]);
        float dy = fminf(py2, s[3][g]) - fmaxf(py1, s[1][g]);
        dx = fmaxf(dx, 0.0f); dy = fmaxf(dy, 0.0f);
        float inter = dx * dy;
        float iou   = inter / (parea + s[4][g] - inter);
        bool v = (s[5][g] != 0.0f);
        if (v && iou > IOU_THR) ignore = true;
        // last matching g wins -> numpy duplicate-scatter semantics
        if (v && ((int)s[6][g] == a) && ((int)s[7][g] == cell)) { match = g; iou_m = iou; }
    }

    float lsum  = 0.0f;
    float cm    = ignore ? 0.0f : 1.0f;   // NOOBJECT_SCALE = 1
    float tconf = 0.0f;
    if (match >= 0) {
        cm    = OBJ_SCALE;
        tconf = iou_m;
        // coord loss (COORD_SCALE = 1)
        float d0 = sx - s[ 8][match];
        float d1 = sy - s[ 9][match];
        float d2 = ow - s[10][match];
        float d3 = oh - s[11][match];
        lsum += d0*d0 + d1*d1 + d2*d2 + d3*d3;
        // class CE (CLASS_SCALE * 2)
        int tcl = (int)s[12][match];
        float lg[NC];
        float m = -1e30f, ltgt = 0.0f;
        #pragma unroll
        for (int c = 0; c < NC; ++c) {     // static indexing only
            lg[c] = base[(5 + c) * HWSZ];
            m = fmaxf(m, lg[c]);
            if (c == tcl) ltgt = lg[c];
        }
        float se = 0.0f;
        #pragma unroll
        for (int c = 0; c < NC; ++c) se += __expf(lg[c] - m);
        float ce = -(ltgt - m - __logf(se));
        lsum += 2.0f * ce;
    }
    float dc = conf - tconf;
    lsum += cm * dc * dc;

    // block reduction: 64-lane shfl, 4 waves via LDS, one atomic per block
    #pragma unroll
    for (int off = 32; off > 0; off >>= 1) lsum += __shfl_down(lsum, off);
    int lane = tid & 63, wid = tid >> 6;
    if (lane == 0) wsum[wid] = lsum;
    __syncthreads();
    if (tid == 0) {
        float bs = wsum[0] + wsum[1] + wsum[2] + wsum[3];
        atomicAdd(out, bs * (1.0f / 16.0f));   // fold /B
    }
}

extern "C" void kernel_launch(void* const* d_in, const int* in_sizes, int n_in,
                              void* d_out, int out_size, void* d_ws, size_t ws_size,
                              hipStream_t stream) {
    const float* output   = (const float*)d_in[0];
    const float* target   = (const float*)d_in[1];
    const void*  gt_valid = d_in[2];
    const float* anchors  = (const float*)d_in[3];
    float* out = (float*)d_out;

    hipMemsetAsync(out, 0, sizeof(float), stream);
    yolo_loss<<<(NB * NA * HWSZ) / 256, 256, 0, stream>>>(output, target, gt_valid, anchors, out);
}

// Round 3
// 30.674 us; speedup vs baseline: 1.1018x; 1.1018x over previous
//
#include <hip/hip_runtime.h>
#include <math.h>

#define NB   16
#define NA   5
#define NC   20
#define NG   32
#define HWSZ 4096
#define WDIM 64
#define NCH  25          // 5 + NC
#define OBJ_SCALE 5.0f

// One thread per (b,a,cell). First 32 lanes of each block redundantly compute
// per-gt prep for this block's (batch, anchor) into LDS; then all 256 threads
// run a div-free ignore/match loop, block-reduce, one atomicAdd per block.
__global__ __launch_bounds__(256) void yolo_loss(
    const float* __restrict__ output,
    const float* __restrict__ target,
    const void*  __restrict__ gt_valid_raw,
    const float* __restrict__ anchors,
    float* __restrict__ out)
{
    __shared__ float4 sbox[NG];   // gt corners x1,y1,x2,y2 (degenerate if invalid)
    __shared__ float2 sthr[NG];   // x: 0.375*garea, y: cellm (cell if valid&&best==a else -1)
    __shared__ float  sga [NG];   // gt area
    __shared__ float  stx [NG], sty[NG], stw[NG], sth2[NG], scls[NG];
    __shared__ float  wsum[4];
    __shared__ int f1, f23;

    int tid  = threadIdx.x;
    int idx  = blockIdx.x * 256 + tid;
    int b    = idx / (NA * HWSZ);      // uniform per block (20480 % 256 == 0)
    int rem  = idx % (NA * HWSZ);
    int a    = rem / HWSZ;             // uniform per block
    int cell = rem % HWSZ;

    if (tid == 0) { f1 = 0; f23 = 0; }
    __syncthreads();

    // --- sniff gt_valid dtype (bool upload ambiguity). Reads bytes [0,512):
    // in-bounds for u8 (512B), i32 (2048B), f32 (2048B).
    const unsigned char* bytes = (const unsigned char*)gt_valid_raw;
    {
        unsigned char c0 = bytes[tid] | bytes[tid + 256];
        int m4 = tid & 3;
        if (c0) { if (m4 == 1) f1 = 1; else if (m4 >= 2) f23 = 1; }
    }
    __syncthreads();

    if (tid < NG) {
        int t = b * NG + tid;
        bool valid;
        if (f1)       valid = bytes[t] != 0;
        else if (f23) valid = ((const float*)gt_valid_raw)[t] != 0.0f;
        else          valid = ((const int*)gt_valid_raw)[t]   != 0;

        const float* tg = target + t * 5;
        float x = tg[0], y = tg[1], w = tg[2], h = tg[3], cls = tg[4];
        const float inv = 1.0f / 32.0f;
        float gx = (x + 0.5f * w) * inv;
        float gy = (y + 0.5f * h) * inv;
        float gw = w * inv, gh = h * inv;
        float garea = gw * gh;

        // best anchor: IOU of (0,0,gw,gh) vs (0,0,aw,ah); first-max wins
        int best = 0; float bi = -1.0f, baw = 1.0f, bah = 1.0f;
        #pragma unroll
        for (int n = 0; n < NA; ++n) {
            float aw_ = anchors[2*n], ah_ = anchors[2*n + 1];
            float inter = fminf(gw, aw_) * fminf(gh, ah_);
            float iou   = inter / (garea + aw_ * ah_ - inter);
            if (iou > bi) { bi = iou; best = n; baw = aw_; bah = ah_; }
        }
        int gi = min(max((int)gx, 0), WDIM - 1);
        int gj = min(max((int)gy, 0), WDIM - 1);

        if (valid) {
            sbox[tid] = make_float4(gx - 0.5f*gw, gy - 0.5f*gh,
                                    gx + 0.5f*gw, gy + 0.5f*gh);
            sthr[tid] = make_float2(0.375f * garea,
                                    (best == a) ? (float)(gj * WDIM + gi) : -1.0f);
        } else {
            sbox[tid] = make_float4(1e30f, 1e30f, -1e30f, -1e30f); // never overlaps
            sthr[tid] = make_float2(0.0f, -1.0f);                  // never matches
        }
        sga [tid] = garea;
        stx [tid] = gx - (float)gi;
        sty [tid] = gy - (float)gj;
        stw [tid] = logf(fmaxf(gw, 1.0f) / baw);
        sth2[tid] = logf(fmaxf(gh, 1.0f) / bah);
        scls[tid] = cls;
    }
    __syncthreads();

    const float* base = output + ((size_t)(b * NA + a) * NCH) * HWSZ + cell;
    float ox = base[0];
    float oy = base[1 * HWSZ];
    float ow = base[2 * HWSZ];
    float oh = base[3 * HWSZ];
    float oc = base[4 * HWSZ];

    float sx   = 1.0f / (1.0f + __expf(-ox));
    float sy   = 1.0f / (1.0f + __expf(-oy));
    float conf = 1.0f / (1.0f + __expf(-oc));
    float pw = __expf(ow) * anchors[2 * a];
    float ph = __expf(oh) * anchors[2 * a + 1];
    float px = sx + (float)(cell & (WDIM - 1));
    float py = sy + (float)(cell >> 6);
    float px1 = px - 0.5f * pw, px2 = px + 0.5f * pw;
    float py1 = py - 0.5f * ph, py2 = py + 0.5f * ph;
    float parea = pw * ph;

    float negc1 = -0.375f * parea;     // inter/union>0.6 <=> inter-0.375*pa > 0.375*ga
    float cellf = (float)cell;
    bool  ignore = false;
    int   match  = -1;                 // last matching g wins (numpy scatter semantics)
    #pragma unroll
    for (int g = 0; g < NG; ++g) {
        float4 bx = sbox[g];
        float2 tc = sthr[g];
        float dx = fminf(px2, bx.z) - fmaxf(px1, bx.x);
        float dy = fminf(py2, bx.w) - fmaxf(py1, bx.y);
        dx = fmaxf(dx, 0.0f); dy = fmaxf(dy, 0.0f);
        ignore |= (fmaf(dx, dy, negc1) > tc.x);
        if (tc.y == cellf) match = g;
    }

    float lsum  = 0.0f;
    float cm    = ignore ? 0.0f : 1.0f;   // NOOBJECT_SCALE = 1
    float tconf = 0.0f;
    if (match >= 0) {
        cm = OBJ_SCALE;
        // exact IOU for the matched gt (one real division, rare threads only)
        float4 bx = sbox[match];
        float dx = fmaxf(fminf(px2, bx.z) - fmaxf(px1, bx.x), 0.0f);
        float dy = fmaxf(fminf(py2, bx.w) - fmaxf(py1, bx.y), 0.0f);
        float inter = dx * dy;
        tconf = inter / (parea + sga[match] - inter);
        // coord loss (COORD_SCALE = 1)
        float d0 = sx - stx [match];
        float d1 = sy - sty [match];
        float d2 = ow - stw [match];
        float d3 = oh - sth2[match];
        lsum += d0*d0 + d1*d1 + d2*d2 + d3*d3;
        // class CE (CLASS_SCALE * 2)
        int tcl = (int)scls[match];
        float lg[NC];
        float m = -1e30f, ltgt = 0.0f;
        #pragma unroll
        for (int c = 0; c < NC; ++c) {     // static indexing only
            lg[c] = base[(5 + c) * HWSZ];
            m = fmaxf(m, lg[c]);
            if (c == tcl) ltgt = lg[c];
        }
        float se = 0.0f;
        #pragma unroll
        for (int c = 0; c < NC; ++c) se += __expf(lg[c] - m);
        float ce = -(ltgt - m - __logf(se));
        lsum += 2.0f * ce;
    }
    float dc = conf - tconf;
    lsum += cm * dc * dc;

    // block reduction: 64-lane shfl, 4 waves via LDS, one atomic per block
    #pragma unroll
    for (int off = 32; off > 0; off >>= 1) lsum += __shfl_down(lsum, off);
    int lane = tid & 63, wid = tid >> 6;
    if (lane == 0) wsum[wid] = lsum;
    __syncthreads();
    if (tid == 0) {
        float bs = wsum[0] + wsum[1] + wsum[2] + wsum[3];
        atomicAdd(out, bs * (1.0f / 16.0f));   // fold /B
    }
}

extern "C" void kernel_launch(void* const* d_in, const int* in_sizes, int n_in,
                              void* d_out, int out_size, void* d_ws, size_t ws_size,
                              hipStream_t stream) {
    const float* output   = (const float*)d_in[0];
    const float* target   = (const float*)d_in[1];
    const void*  gt_valid = d_in[2];
    const float* anchors  = (const float*)d_in[3];
    float* out = (float*)d_out;

    hipMemsetAsync(out, 0, sizeof(float), stream);
    yolo_loss<<<(NB * NA * HWSZ) / 256, 256, 0, stream>>>(output, target, gt_valid, anchors, out);
}

// Round 4
// 15.597 us; speedup vs baseline: 2.1669x; 1.9667x over previous
//
#include <hip/hip_runtime.h>
#include <math.h>

#define NB   16
#define NA   5
#define NC   20
#define NG   32
#define HWSZ 4096
#define WDIM 64
#define NCH  25          // 5 + NC
#define OBJ_SCALE 5.0f
#define NBLK ((NB * NA * HWSZ) / 256)   // 1280

// One thread per (b,a,cell). Lanes 0..31 of wave 0 redundantly compute per-gt
// prep for this block's (batch, anchor) into LDS; all 256 threads run a
// div-free ignore/match loop; block partial goes to ws[blockIdx] (no atomic).
__global__ __launch_bounds__(256) void yolo_loss(
    const float* __restrict__ output,
    const float* __restrict__ target,
    const void*  __restrict__ gt_valid_raw,
    const float* __restrict__ anchors,
    float* __restrict__ partials,       // null => atomicAdd(out) fallback
    float* __restrict__ out)
{
    __shared__ float4 sbox[NG];   // gt corners x1,y1,x2,y2 (degenerate if invalid)
    __shared__ float2 sthr[NG];   // x: 0.375*garea, y: cell if (valid && best==a) else -1
    __shared__ float  sga [NG];   // gt area
    __shared__ float  stx [NG], sty[NG], stw[NG], sth2[NG], scls[NG];
    __shared__ float  wsum[4];

    int tid  = threadIdx.x;
    int idx  = blockIdx.x * 256 + tid;
    int b    = idx / (NA * HWSZ);      // uniform per block (20480 % 256 == 0)
    int rem  = idx % (NA * HWSZ);
    int a    = rem / HWSZ;             // uniform per block
    int cell = rem % HWSZ;

    // --- wave-0 prep: dtype sniff via ballot (no barriers), then per-gt fields
    if (tid < 64) {
        const unsigned char* bytes = (const unsigned char*)gt_valid_raw;
        // Sniff gt_valid dtype from first 256 bytes (in-bounds for u8 512B,
        // i32/f32 2048B). u8 bool -> nonzero bytes at (i&3)==1 positions;
        // f32 1.0f (00 00 80 3F) -> nonzero only at (i&3)>=2; i32 1 -> only ==0.
        unsigned char bb = bytes[tid] | bytes[tid + 64] | bytes[tid + 128] | bytes[tid + 192];
        unsigned long long m = __ballot(bb != 0);
        bool is_u8  = (m & 0x2222222222222222ULL) != 0ULL;
        bool is_f32 = !is_u8 && (m & 0xCCCCCCCCCCCCCCCCULL) != 0ULL;

        if (tid < NG) {
            int t = b * NG + tid;
            bool valid;
            if (is_u8)       valid = bytes[t] != 0;
            else if (is_f32) valid = ((const float*)gt_valid_raw)[t] != 0.0f;
            else             valid = ((const int*)gt_valid_raw)[t]   != 0;

            const float* tg = target + t * 5;
            float x = tg[0], y = tg[1], w = tg[2], h = tg[3], cls = tg[4];
            const float inv = 1.0f / 32.0f;
            float gx = (x + 0.5f * w) * inv;
            float gy = (y + 0.5f * h) * inv;
            float gw = w * inv, gh = h * inv;
            float garea = gw * gh;

            // best anchor: IOU of (0,0,gw,gh) vs (0,0,aw,ah); first-max wins
            int best = 0; float bi = -1.0f, baw = 1.0f, bah = 1.0f;
            #pragma unroll
            for (int n = 0; n < NA; ++n) {
                float aw_ = anchors[2*n], ah_ = anchors[2*n + 1];
                float inter = fminf(gw, aw_) * fminf(gh, ah_);
                float iou   = inter / (garea + aw_ * ah_ - inter);
                if (iou > bi) { bi = iou; best = n; baw = aw_; bah = ah_; }
            }
            int gi = min(max((int)gx, 0), WDIM - 1);
            int gj = min(max((int)gy, 0), WDIM - 1);

            if (valid) {
                sbox[tid] = make_float4(gx - 0.5f*gw, gy - 0.5f*gh,
                                        gx + 0.5f*gw, gy + 0.5f*gh);
                sthr[tid] = make_float2(0.375f * garea,
                                        (best == a) ? (float)(gj * WDIM + gi) : -1.0f);
            } else {
                sbox[tid] = make_float4(1e30f, 1e30f, -1e30f, -1e30f); // never overlaps
                sthr[tid] = make_float2(0.0f, -1.0f);                  // never matches
            }
            sga [tid] = garea;
            stx [tid] = gx - (float)gi;
            sty [tid] = gy - (float)gj;
            stw [tid] = logf(fmaxf(gw, 1.0f) / baw);
            sth2[tid] = logf(fmaxf(gh, 1.0f) / bah);
            scls[tid] = cls;
        }
    }
    __syncthreads();

    const float* base = output + ((size_t)(b * NA + a) * NCH) * HWSZ + cell;
    float ox = base[0];
    float oy = base[1 * HWSZ];
    float ow = base[2 * HWSZ];
    float oh = base[3 * HWSZ];
    float oc = base[4 * HWSZ];

    float sx   = 1.0f / (1.0f + __expf(-ox));
    float sy   = 1.0f / (1.0f + __expf(-oy));
    float conf = 1.0f / (1.0f + __expf(-oc));
    float pw = __expf(ow) * anchors[2 * a];
    float ph = __expf(oh) * anchors[2 * a + 1];
    float px = sx + (float)(cell & (WDIM - 1));
    float py = sy + (float)(cell >> 6);
    float px1 = px - 0.5f * pw, px2 = px + 0.5f * pw;
    float py1 = py - 0.5f * ph, py2 = py + 0.5f * ph;
    float parea = pw * ph;

    float negc1 = -0.375f * parea;     // inter/union>0.6 <=> inter-0.375*pa > 0.375*ga
    float cellf = (float)cell;
    bool  ignore = false;
    int   match  = -1;                 // last matching g wins (numpy scatter semantics)
    #pragma unroll
    for (int g = 0; g < NG; ++g) {
        float4 bx = sbox[g];
        float2 tc = sthr[g];
        float dx = fminf(px2, bx.z) - fmaxf(px1, bx.x);
        float dy = fminf(py2, bx.w) - fmaxf(py1, bx.y);
        dx = fmaxf(dx, 0.0f); dy = fmaxf(dy, 0.0f);
        ignore |= (fmaf(dx, dy, negc1) > tc.x);
        if (tc.y == cellf) match = g;
    }

    float lsum  = 0.0f;
    float cm    = ignore ? 0.0f : 1.0f;   // NOOBJECT_SCALE = 1
    float tconf = 0.0f;
    if (match >= 0) {
        cm = OBJ_SCALE;
        // exact IOU for the matched gt (one real division, rare threads only)
        float4 bx = sbox[match];
        float dx = fmaxf(fminf(px2, bx.z) - fmaxf(px1, bx.x), 0.0f);
        float dy = fmaxf(fminf(py2, bx.w) - fmaxf(py1, bx.y), 0.0f);
        float inter = dx * dy;
        tconf = inter / (parea + sga[match] - inter);
        // coord loss (COORD_SCALE = 1)
        float d0 = sx - stx [match];
        float d1 = sy - sty [match];
        float d2 = ow - stw [match];
        float d3 = oh - sth2[match];
        lsum += d0*d0 + d1*d1 + d2*d2 + d3*d3;
        // class CE (CLASS_SCALE * 2)
        int tcl = (int)scls[match];
        float lg[NC];
        float m = -1e30f, ltgt = 0.0f;
        #pragma unroll
        for (int c = 0; c < NC; ++c) {     // static indexing only
            lg[c] = base[(5 + c) * HWSZ];
            m = fmaxf(m, lg[c]);
            if (c == tcl) ltgt = lg[c];
        }
        float se = 0.0f;
        #pragma unroll
        for (int c = 0; c < NC; ++c) se += __expf(lg[c] - m);
        float ce = -(ltgt - m - __logf(se));
        lsum += 2.0f * ce;
    }
    float dc = conf - tconf;
    lsum += cm * dc * dc;

    // block reduction: 64-lane shfl, 4 waves via LDS
    #pragma unroll
    for (int off = 32; off > 0; off >>= 1) lsum += __shfl_down(lsum, off);
    int lane = tid & 63, wid = tid >> 6;
    if (lane == 0) wsum[wid] = lsum;
    __syncthreads();
    if (tid == 0) {
        float bs = wsum[0] + wsum[1] + wsum[2] + wsum[3];
        if (partials) partials[blockIdx.x] = bs;          // no atomic, no pre-zero
        else          atomicAdd(out, bs * (1.0f / 16.0f)); // fallback path
    }
}

// Tree-reduce the 1280 block partials -> out[0]. One block, deterministic.
__global__ __launch_bounds__(256) void yolo_reduce(const float* __restrict__ partials,
                                                   float* __restrict__ out)
{
    int tid = threadIdx.x;
    float s = 0.0f;
    #pragma unroll
    for (int i = 0; i < NBLK / 256; ++i) s += partials[i * 256 + tid];
    #pragma unroll
    for (int off = 32; off > 0; off >>= 1) s += __shfl_down(s, off);
    __shared__ float wsum[4];
    int lane = tid & 63, wid = tid >> 6;
    if (lane == 0) wsum[wid] = s;
    __syncthreads();
    if (tid == 0) out[0] = (wsum[0] + wsum[1] + wsum[2] + wsum[3]) * (1.0f / 16.0f);
}

extern "C" void kernel_launch(void* const* d_in, const int* in_sizes, int n_in,
                              void* d_out, int out_size, void* d_ws, size_t ws_size,
                              hipStream_t stream) {
    const float* output   = (const float*)d_in[0];
    const float* target   = (const float*)d_in[1];
    const void*  gt_valid = d_in[2];
    const float* anchors  = (const float*)d_in[3];
    float* out = (float*)d_out;

    if (ws_size >= NBLK * sizeof(float)) {
        float* partials = (float*)d_ws;
        yolo_loss<<<NBLK, 256, 0, stream>>>(output, target, gt_valid, anchors, partials, out);
        yolo_reduce<<<1, 256, 0, stream>>>(partials, out);
    } else {
        hipMemsetAsync(out, 0, sizeof(float), stream);
        yolo_loss<<<NBLK, 256, 0, stream>>>(output, target, gt_valid, anchors, nullptr, out);
    }
}